// Round 13
// baseline (642.192 us; speedup 1.0000x reference)
//
#include <hip/hip_runtime.h>

// LIIF render, fully fused, fp16 MFMA. Round 14 (resubmit — R12 bench was a
// GPUAcquisitionTimeout, kernel never ran): 16x16x32 -> 32x32x16 shape swap
// inside the proven R10 schedule.
// R13 A/B resolved: R10(2-frag peel)=570us counter-level < R13(4-frag)=585
// < R11(4-frag+setprio)=598. Both R11 additions were regressions; R10 is
// the base. This round raises the CEILING instead of the schedule:
// measured f16 MFMA ceilings: 16x16 = 2075 TF, 32x32 = 2382-2495 TF
// (4061 vs 3378 FLOP/cy) -> the 16x16 shape wastes ~17% of the matrix pipe.
// Shape swap, NOT a new pipeline (every R4-R12 pipeline attempt spilled):
//  - wave tile 64 feats x 128 rows as 2x4 tiles of 32x32; per K=32 step:
//    same 8 LDS b128 reads (32 regs), 4 A-frag loads (h-major order ->
//    same-acc reuse gap = 8 instrs), acc[2][4] f32x16 = 128 AGPRs (same
//    footprint as the proven acc[4][8]).
//  - R10's lgkm-only barriers + apre0/1 2-frag cross-layer chain verbatim.
//  - Layouts per verified m74/m101 mapping: A/B lane: row=l&31,k=(l>>5)*8;
//    C/D: col=l&31, row=(reg&3)+8*(reg>>2)+4*(l>>5) -> epilogue still
//    writes f16x4 of 4 consecutive feats. B-read bank pattern unchanged.
//  - Final 256->16 layer stays 16x16 (R10 code unchanged).
//  - Accumulation k-ascending; intra-K=32 chunking now 16+16 chained
//    (fp32 accumulate -> absmax expected to hold at 0.00390625).
// Gates: (1) passed & absmax<=0.00390625 else revert-R10+plateau;
// (2) VGPR 128, FETCH ~8.5MB, WRITE ~8.4MB; (3) dur 570 -> ~505-540
// counter-level, MfmaUtil 39-44.

typedef _Float16 f16;
typedef _Float16 f16x8 __attribute__((ext_vector_type(8)));
typedef _Float16 f16x4 __attribute__((ext_vector_type(4)));
typedef float    f32x4 __attribute__((ext_vector_type(4)));
typedef float    f32x16 __attribute__((ext_vector_type(16)));

#define MFMA(a, b, c)   __builtin_amdgcn_mfma_f32_16x16x32_f16((a), (b), (c), 0, 0, 0)
#define MFMA32(a, b, c) __builtin_amdgcn_mfma_f32_32x32x16_f16((a), (b), (c), 0, 0, 0)

constexpr int HF = 64, WF = 64;         // feature map dims
constexpr int HO = 256, WO = 256;       // output dims
constexpr int Q = HO * WO;              // 65536 queries per image
constexpr int D = 256;                  // hidden width
constexpr int K0P = 96;                 // input dim 68 padded to 96 (3 k-steps)
constexpr int STR = 264;                // LDS row stride (halves)
constexpr int R = 128;                  // query rows per block

// workspace layout (bytes)
constexpr size_t OFF_FEAT = 0;                        // 4*4096*64*2 = 2 MiB
constexpr size_t OFF_W0   = 2097152;                  // 256*96*2
constexpr size_t OFF_W1   = OFF_W0 + 256 * 96 * 2;    // 256*256*2
constexpr size_t OFF_W2   = OFF_W1 + 256 * 256 * 2;
constexpr size_t OFF_W3   = OFF_W2 + 256 * 256 * 2;
constexpr size_t OFF_W4   = OFF_W3 + 256 * 256 * 2;   // 16*256*2

// lgkm-only barrier: waits LDS ops (the actual hazard) but lets global
// loads (A-prefetch) stay in flight across the barrier.
__device__ __forceinline__ void bar() {
  asm volatile("s_waitcnt lgkmcnt(0)" ::: "memory");
  __builtin_amdgcn_s_barrier();
}

// (N,C,Hf,Wf) fp32 -> (N, Hf*Wf, C) fp16 so a gather row is 128 B contiguous.
__global__ void prep_feat(const float* __restrict__ f, f16* __restrict__ ft) {
  int idx = blockIdx.x * 256 + threadIdx.x;          // 1,048,576 total
  int c = idx & 63, p = (idx >> 6) & 4095, n = idx >> 18;
  ft[idx] = (f16)f[((((size_t)n << 6) | c) << 12) | p];
}

// w (K x N) fp32 -> wt (Npad x Kpad) fp16, zero-padded.
__global__ void prep_w(const float* __restrict__ w, f16* __restrict__ wt,
                       int K, int N, int Kpad, int Npad) {
  int idx = blockIdx.x * 256 + threadIdx.x;
  if (idx >= Npad * Kpad) return;
  int k = idx % Kpad, n = idx / Kpad;
  wt[idx] = (f16)((k < K && n < N) ? w[k * N + n] : 0.0f);
}

// Geometry for query q, tap (vx, vy): feature pixel p and rel coords.
__device__ __forceinline__ void tap_geom(int q, float vx, float vy,
                                         int& p, float& rel0, float& rel1) {
  int qy = q >> 8, qx = q & (WO - 1);
  float cy0 = (float)(2 * qy + 1) * (1.0f / HO) - 1.0f;
  float cx0 = (float)(2 * qx + 1) * (1.0f / WO) - 1.0f;
  float cy = cy0 + vx * (1.0f / HF) + 1e-6f;
  float cx = cx0 + vy * (1.0f / WF) + 1e-6f;
  cy = fminf(fmaxf(cy, -1.0f + 1e-6f), 1.0f - 1e-6f);
  cx = fminf(fmaxf(cx, -1.0f + 1e-6f), 1.0f - 1e-6f);
  int iy = (int)rintf(((cy + 1.0f) * (float)HF - 1.0f) * 0.5f);  // rndne == jnp.round
  int ix = (int)rintf(((cx + 1.0f) * (float)WF - 1.0f) * 0.5f);
  iy = min(max(iy, 0), HF - 1);
  ix = min(max(ix, 0), WF - 1);
  p = (iy << 6) | ix;
  rel0 = (cy0 - ((float)(2 * iy + 1) * (1.0f / HF) - 1.0f)) * (float)HF;
  rel1 = (cx0 - ((float)(2 * ix + 1) * (1.0f / WF) - 1.0f)) * (float)WF;
}

// Blend weight for tap t, query q: preds[t] pairs with areas[3-t].
__device__ __forceinline__ float blend_wt(int q, int t) {
  float a[4], tot = 0.0f;
#pragma unroll
  for (int u = 0; u < 4; ++u) {
    int p; float r0, r1;
    tap_geom(q, (u & 2) ? 1.0f : -1.0f, (u & 1) ? 1.0f : -1.0f, p, r0, r1);
    a[u] = fabsf(r0 * r1) + 1e-9f;
    tot += a[u];
  }
  float sel = (t == 0) ? a[3] : (t == 1) ? a[2] : (t == 2) ? a[1] : a[0];
  return sel / tot;
}

// One hidden layer on the shared 128-row tile, in place, 32x32x16 MFMA.
// m = out-feature (wave owns feats [wv*64, wv*64+64) as 2 tiles of 32),
// n = 128 query rows (4 tiles of 32). acc[2][4] f32x16 = 128 AGPRs.
// A-frag(mt,h,s): lane supplies A[wv*64+mt*32+r32][s*32+h*16+hi*8 .. +8).
// B-frag(nt,h,s): lane supplies X[nt*32+r32][s*32+h*16+hi*8 .. +8).
// R10's schedule: rolled s-loop, 4 A-loads interleaved with 4x4-MFMA
// bursts (h-major: same-acc reuse gap = 8 instructions), s=0's h=0 A pair
// arrives via the apre0/1 cross-layer prefetch chain; before the
// pre-epilogue barrier we issue the NEXT consumer's pair.
template <int KSTEPS, int KPAD>
__device__ __forceinline__ void mlp_layer(f16* X, const f16* __restrict__ wt,
                                          const float* __restrict__ bv,
                                          int wv, int r32, int hi,
                                          f16x8& apre0, f16x8& apre1,
                                          const f16* __restrict__ nxt,
                                          int nstride) {
  f32x16 acc[2][4];
#pragma unroll
  for (int mt = 0; mt < 2; ++mt)
#pragma unroll
    for (int nt = 0; nt < 4; ++nt) acc[mt][nt] = 0.0f;

  const f16* ap = wt + (wv * 64 + r32) * KPAD + hi * 8;  // A[m=r32+32mt][k]
  const f16* bp = X + r32 * STR + hi * 8;                // B[n=r32+32nt][k]

  // ---- s = 0 (peeled): h=0 from the prefetch chain; h=1 inline ----
  {
    f16x8 b0[4], b1[4];
#pragma unroll
    for (int nt = 0; nt < 4; ++nt) {
      b0[nt] = *(const f16x8*)(bp + nt * 32 * STR);
      b1[nt] = *(const f16x8*)(bp + 16 + nt * 32 * STR);
    }
#pragma unroll
    for (int nt = 0; nt < 4; ++nt) acc[0][nt] = MFMA32(apre0, b0[nt], acc[0][nt]);
#pragma unroll
    for (int nt = 0; nt < 4; ++nt) acc[1][nt] = MFMA32(apre1, b0[nt], acc[1][nt]);
    f16x8 a = *(const f16x8*)(ap + 16);                      // mt0, h1
#pragma unroll
    for (int nt = 0; nt < 4; ++nt) acc[0][nt] = MFMA32(a, b1[nt], acc[0][nt]);
    a = *(const f16x8*)(ap + 32 * KPAD + 16);                // mt1, h1
#pragma unroll
    for (int nt = 0; nt < 4; ++nt) acc[1][nt] = MFMA32(a, b1[nt], acc[1][nt]);
  }
  // ---- s = 1..KSTEPS-1: rolled, R10's interleave at the new shape ----
#pragma unroll 1
  for (int s = 1; s < KSTEPS; ++s) {
    f16x8 b0[4], b1[4];
#pragma unroll
    for (int nt = 0; nt < 4; ++nt) {
      b0[nt] = *(const f16x8*)(bp + s * 32 + nt * 32 * STR);
      b1[nt] = *(const f16x8*)(bp + s * 32 + 16 + nt * 32 * STR);
    }
    f16x8 a = *(const f16x8*)(ap + s * 32);                  // mt0, h0
#pragma unroll
    for (int nt = 0; nt < 4; ++nt) acc[0][nt] = MFMA32(a, b0[nt], acc[0][nt]);
    a = *(const f16x8*)(ap + s * 32 + 32 * KPAD);            // mt1, h0
#pragma unroll
    for (int nt = 0; nt < 4; ++nt) acc[1][nt] = MFMA32(a, b0[nt], acc[1][nt]);
    a = *(const f16x8*)(ap + s * 32 + 16);                   // mt0, h1
#pragma unroll
    for (int nt = 0; nt < 4; ++nt) acc[0][nt] = MFMA32(a, b1[nt], acc[0][nt]);
    a = *(const f16x8*)(ap + s * 32 + 16 + 32 * KPAD);       // mt1, h1
#pragma unroll
    for (int nt = 0; nt < 4; ++nt) acc[1][nt] = MFMA32(a, b1[nt], acc[1][nt]);
  }

  // Prefetch the NEXT consumer's first A-frag pair; stays in flight across
  // the lgkm-only barriers and the epilogue (~600+cy window).
  apre0 = *(const f16x8*)(nxt);
  apre1 = *(const f16x8*)(nxt + nstride);

  bar();   // all reads of X done before overwrite (lgkm-only)
  // D: col(query)=r32, row(feat)=(reg&3)+8*(reg>>2)+4*hi, reg=4g+j.
  // Lane holds 4 consecutive feats per reg-group -> f16x4 LDS writes.
#pragma unroll
  for (int mt = 0; mt < 2; ++mt) {
#pragma unroll
    for (int g = 0; g < 4; ++g) {
      float4 bb = *(const float4*)(bv + wv * 64 + mt * 32 + g * 8 + hi * 4);
#pragma unroll
      for (int nt = 0; nt < 4; ++nt) {
        f16x4 y;
        y[0] = (f16)fmaxf(acc[mt][nt][g * 4 + 0] + bb.x, 0.0f);
        y[1] = (f16)fmaxf(acc[mt][nt][g * 4 + 1] + bb.y, 0.0f);
        y[2] = (f16)fmaxf(acc[mt][nt][g * 4 + 2] + bb.z, 0.0f);
        y[3] = (f16)fmaxf(acc[mt][nt][g * 4 + 3] + bb.w, 0.0f);
        *(f16x4*)(X + (nt * 32 + r32) * STR + wv * 64 + mt * 32 + g * 8 + hi * 4) = y;
      }
    }
  }
  bar();
}

__global__ __launch_bounds__(256, 2) void liif_main(
    const f16* __restrict__ featT,
    const f16* __restrict__ wt0, const f16* __restrict__ wt1,
    const f16* __restrict__ wt2, const f16* __restrict__ wt3,
    const f16* __restrict__ wt4,
    const float* __restrict__ b0, const float* __restrict__ b1,
    const float* __restrict__ b2, const float* __restrict__ b3,
    const float* __restrict__ b4, float* __restrict__ out) {
  __shared__ __attribute__((aligned(16))) f16 X[R * STR];   // 67.6 KB
  const int tid = threadIdx.x;
  const int wv = tid >> 6;
  const int lane = tid & 63;
  const int row0 = blockIdx.x * R;               // rows = n*Q + q, 128 per block
  const int n = row0 >> 16;
  const int q0 = row0 & (Q - 1);
  const int col = lane & 15, quad = lane >> 4;   // 16x16 indices (final layer)
  const int r32 = lane & 31, hi = lane >> 5;     // 32x32 indices (hidden layers)

  float oacc[2][4] = {{0, 0, 0, 0}, {0, 0, 0, 0}};
  float bias4[4];
#pragma unroll
  for (int i = 0; i < 4; ++i) bias4[i] = (i < 3) ? b4[i] : 0.0f;

  // Per-layer A base pointers for this thread (prefetch chain targets).
  // Hidden layers: 32x32 layout (row=r32, k-offset hi*8).
  const f16* a0b = wt0 + (wv * 64 + r32) * K0P + hi * 8;
  const f16* a1b = wt1 + (wv * 64 + r32) * D + hi * 8;
  const f16* a2b = wt2 + (wv * 64 + r32) * D + hi * 8;
  const f16* a3b = wt3 + (wv * 64 + r32) * D + hi * 8;
  const f16* a4b = wt4 + col * D + quad * 8;     // final layer: 16x16 layout

  // Initial prefetch: layer 0, s=0, h=0, mt=0 and mt=1.
  f16x8 apre0 = *(const f16x8*)(a0b);
  f16x8 apre1 = *(const f16x8*)(a0b + 32 * K0P);

#pragma unroll 1
  for (int t = 0; t < 4; ++t) {
    const float vx = (t & 2) ? 1.0f : -1.0f;
    const float vy = (t & 1) ? 1.0f : -1.0f;

    bar();   // previous tap's reads of X complete
    // ---- gather X0: 64 feat + rel(2) + rel_cell(2), pad to 96 ----
    {
      const int gr = tid >> 1, hf = tid & 1;   // 2 threads per row, 64 B each
      int p; float r0, r1;
      tap_geom(q0 + gr, vx, vy, p, r0, r1);
      const f16x8* src = (const f16x8*)(featT + (((size_t)n << 12) + p) * 64 + hf * 32);
      f16x8* dst = (f16x8*)(X + gr * STR + hf * 32);
      dst[0] = src[0]; dst[1] = src[1]; dst[2] = src[2]; dst[3] = src[3];
      if (tid < R) {
        int p2; float s0, s1;
        tap_geom(q0 + tid, vx, vy, p2, s0, s1);
        f16* xr = X + tid * STR;
        f16x4 relv = {(f16)s0, (f16)s1, (f16)0.5f, (f16)0.5f};
        *(f16x4*)(xr + 64) = relv;
        f16x4 z4 = {0, 0, 0, 0};
        f16x8 z8 = {0, 0, 0, 0, 0, 0, 0, 0};
        *(f16x4*)(xr + 68) = z4;     // zero pad cols 68..95
        *(f16x8*)(xr + 72) = z8;
        *(f16x8*)(xr + 80) = z8;
        *(f16x8*)(xr + 88) = z8;
      }
    }
    bar();

    mlp_layer<3, K0P>(X, wt0, b0, wv, r32, hi, apre0, apre1, a1b, 32 * D);
    mlp_layer<8, D>(X, wt1, b1, wv, r32, hi, apre0, apre1, a2b, 32 * D);
    mlp_layer<8, D>(X, wt2, b2, wv, r32, hi, apre0, apre1, a3b, 32 * D);
    mlp_layer<8, D>(X, wt3, b3, wv, r32, hi, apre0, apre1, a4b, 32);

    // ---- final layer 256 -> 16 (3 real feats); 16x16x32, as in R10 ----
    // s=0,1 A-frags arrive prefetched (apre0/1); s>=2 inline.
    f32x4 facc[2];
    facc[0] = 0.0f; facc[1] = 0.0f;
    {
      const f16* bp = X + (wv * 32 + col) * STR + quad * 8;  // B[n=query]
      f16x8 bq0 = *(const f16x8*)(bp);
      f16x8 bq1 = *(const f16x8*)(bp + 16 * STR);
      facc[0] = MFMA(apre0, bq0, facc[0]);
      facc[1] = MFMA(apre0, bq1, facc[1]);
      bq0 = *(const f16x8*)(bp + 32);
      bq1 = *(const f16x8*)(bp + 16 * STR + 32);
      facc[0] = MFMA(apre1, bq0, facc[0]);
      facc[1] = MFMA(apre1, bq1, facc[1]);
#pragma unroll 1
      for (int s = 2; s < 8; ++s) {
        f16x8 a = *(const f16x8*)(a4b + s * 32);
        f16x8 c0 = *(const f16x8*)(bp + s * 32);
        f16x8 c1 = *(const f16x8*)(bp + 16 * STR + s * 32);
        facc[0] = MFMA(a, c0, facc[0]);
        facc[1] = MFMA(a, c1, facc[1]);
      }
    }
    // D: row=feat=quad*4+i, col=query. Blend into oacc.
#pragma unroll
    for (int nt = 0; nt < 2; ++nt) {
      int q = q0 + wv * 32 + nt * 16 + col;
      float w = blend_wt(q, t);
#pragma unroll
      for (int i = 0; i < 4; ++i) oacc[nt][i] += (facc[nt][i] + bias4[i]) * w;
    }

    // Prefetch layer-0 A for the NEXT tap (crosses tap barrier + gather).
    apre0 = *(const f16x8*)(a0b);
    apre1 = *(const f16x8*)(a0b + 32 * K0P);
  }

  // out[n][c][q]; lanes with quad==0 hold feats 0..3 (3 real) for their queries
  if (quad == 0) {
#pragma unroll
    for (int nt = 0; nt < 2; ++nt) {
      int q = q0 + wv * 32 + nt * 16 + col;
#pragma unroll
      for (int c = 0; c < 3; ++c)
        out[(((size_t)(n * 3 + c)) << 16) + q] = oacc[nt][c];
    }
  }
}

extern "C" void kernel_launch(void* const* d_in, const int* in_sizes, int n_in,
                              void* d_out, int out_size, void* d_ws, size_t ws_size,
                              hipStream_t stream) {
  const float* feat = (const float*)d_in[0];
  const float* w0 = (const float*)d_in[1];
  const float* b0 = (const float*)d_in[2];
  const float* w1 = (const float*)d_in[3];
  const float* b1 = (const float*)d_in[4];
  const float* w2 = (const float*)d_in[5];
  const float* b2 = (const float*)d_in[6];
  const float* w3 = (const float*)d_in[7];
  const float* b3 = (const float*)d_in[8];
  const float* w4 = (const float*)d_in[9];
  const float* b4 = (const float*)d_in[10];

  char* ws = (char*)d_ws;
  f16* featT = (f16*)(ws + OFF_FEAT);
  f16* wt0 = (f16*)(ws + OFF_W0);
  f16* wt1 = (f16*)(ws + OFF_W1);
  f16* wt2 = (f16*)(ws + OFF_W2);
  f16* wt3 = (f16*)(ws + OFF_W3);
  f16* wt4 = (f16*)(ws + OFF_W4);

  prep_feat<<<4096, 256, 0, stream>>>(feat, featT);
  prep_w<<<(256 * 96 + 255) / 256, 256, 0, stream>>>(w0, wt0, 68, 256, 96, 256);
  prep_w<<<256, 256, 0, stream>>>(w1, wt1, 256, 256, 256, 256);
  prep_w<<<256, 256, 0, stream>>>(w2, wt2, 256, 256, 256, 256);
  prep_w<<<256, 256, 0, stream>>>(w3, wt3, 256, 256, 256, 256);
  prep_w<<<(16 * 256 + 255) / 256, 256, 0, stream>>>(w4, wt4, 256, 3, 256, 16);

  liif_main<<<Q * 4 / R, 256, 0, stream>>>(featT, wt0, wt1, wt2, wt3, wt4,
                                           b0, b1, b2, b3, b4, (float*)d_out);
}

// Round 15
// 588.332 us; speedup vs baseline: 1.0915x; 1.0915x over previous
//
#include <hip/hip_runtime.h>

// LIIF render, fully fused, fp16 MFMA. Round 15 (resubmit — R14 bench was a
// GPUAcquisitionTimeout, kernel never ran): revert to R10, the best verified
// kernel (588.5us bench / 570us counter, measured in Round 8).
// Session ledger at this structure:
//   R3 606 -> R10 (lgkm-only barriers + 2-frag cross-layer A-prefetch) 588.
//   Regressions, each isolated: setprio (R11, lockstep regime), 4-frag peel
//   (R13), per-step ping-pong (R12, spill), occupancy R=64 (R9), n-half
//   split (R5-R7, spill), wave-owns-rows (R8, spill), 32x32 (R14: fewer,
//   longer MFMAs = coarser interleave slots at 2 waves/SIMD).
// Structural ceiling arithmetic: MfmaUtil*dur = 211us ~= the 16x16-f16 pipe
// floor (4.72e11 FLOP / 2075 TF = 227us) -> the matrix pipe is near-minimal
// when busy; the 2.6x gap is non-overlapped load/VALU/barrier time at
// 2 waves/SIMD (LDS-pinned), and every deeper software pipeline exceeded
// the ~128-arch-VGPR envelope (6 spills). Further gains need asm-level
// counted-vmcnt scheduling outside hipcc's allocator behavior.
// Mechanism kept from R10:
//  - lgkm-only barriers: {s_waitcnt lgkmcnt(0); s_barrier} — LDS hazards
//    need lgkm ordering only; global A-prefetch loads stay in flight
//    across barriers.
//  - Chained 2-frag A-prefetch: each layer issues the NEXT consumer's s=0
//    mt=0,1 weight frags before its pre-epilogue barrier; consumed as the
//    first 16 MFMAs after the next barrier.
// Gates: VGPR 128, FETCH ~8.5MB, WRITE ~8.4MB, MfmaUtil ~37,
// dur ~570-585 counter-level, absmax exactly 0.00390625.

typedef _Float16 f16;
typedef _Float16 f16x8 __attribute__((ext_vector_type(8)));
typedef _Float16 f16x4 __attribute__((ext_vector_type(4)));
typedef float    f32x4 __attribute__((ext_vector_type(4)));

#define MFMA(a, b, c) __builtin_amdgcn_mfma_f32_16x16x32_f16((a), (b), (c), 0, 0, 0)

constexpr int HF = 64, WF = 64;         // feature map dims
constexpr int HO = 256, WO = 256;       // output dims
constexpr int Q = HO * WO;              // 65536 queries per image
constexpr int D = 256;                  // hidden width
constexpr int K0P = 96;                 // input dim 68 padded to 96 (3 k-steps)
constexpr int STR = 264;                // LDS row stride (halves)
constexpr int R = 128;                  // query rows per block

// workspace layout (bytes)
constexpr size_t OFF_FEAT = 0;                        // 4*4096*64*2 = 2 MiB
constexpr size_t OFF_W0   = 2097152;                  // 256*96*2
constexpr size_t OFF_W1   = OFF_W0 + 256 * 96 * 2;    // 256*256*2
constexpr size_t OFF_W2   = OFF_W1 + 256 * 256 * 2;
constexpr size_t OFF_W3   = OFF_W2 + 256 * 256 * 2;
constexpr size_t OFF_W4   = OFF_W3 + 256 * 256 * 2;   // 16*256*2

// lgkm-only barrier: waits LDS ops (the actual hazard) but lets global
// loads (A-prefetch) stay in flight across the barrier.
__device__ __forceinline__ void bar() {
  asm volatile("s_waitcnt lgkmcnt(0)" ::: "memory");
  __builtin_amdgcn_s_barrier();
}

// (N,C,Hf,Wf) fp32 -> (N, Hf*Wf, C) fp16 so a gather row is 128 B contiguous.
__global__ void prep_feat(const float* __restrict__ f, f16* __restrict__ ft) {
  int idx = blockIdx.x * 256 + threadIdx.x;          // 1,048,576 total
  int c = idx & 63, p = (idx >> 6) & 4095, n = idx >> 18;
  ft[idx] = (f16)f[((((size_t)n << 6) | c) << 12) | p];
}

// w (K x N) fp32 -> wt (Npad x Kpad) fp16, zero-padded.
__global__ void prep_w(const float* __restrict__ w, f16* __restrict__ wt,
                       int K, int N, int Kpad, int Npad) {
  int idx = blockIdx.x * 256 + threadIdx.x;
  if (idx >= Npad * Kpad) return;
  int k = idx % Kpad, n = idx / Kpad;
  wt[idx] = (f16)((k < K && n < N) ? w[k * N + n] : 0.0f);
}

// Geometry for query q, tap (vx, vy): feature pixel p and rel coords.
__device__ __forceinline__ void tap_geom(int q, float vx, float vy,
                                         int& p, float& rel0, float& rel1) {
  int qy = q >> 8, qx = q & (WO - 1);
  float cy0 = (float)(2 * qy + 1) * (1.0f / HO) - 1.0f;
  float cx0 = (float)(2 * qx + 1) * (1.0f / WO) - 1.0f;
  float cy = cy0 + vx * (1.0f / HF) + 1e-6f;
  float cx = cx0 + vy * (1.0f / WF) + 1e-6f;
  cy = fminf(fmaxf(cy, -1.0f + 1e-6f), 1.0f - 1e-6f);
  cx = fminf(fmaxf(cx, -1.0f + 1e-6f), 1.0f - 1e-6f);
  int iy = (int)rintf(((cy + 1.0f) * (float)HF - 1.0f) * 0.5f);  // rndne == jnp.round
  int ix = (int)rintf(((cx + 1.0f) * (float)WF - 1.0f) * 0.5f);
  iy = min(max(iy, 0), HF - 1);
  ix = min(max(ix, 0), WF - 1);
  p = (iy << 6) | ix;
  rel0 = (cy0 - ((float)(2 * iy + 1) * (1.0f / HF) - 1.0f)) * (float)HF;
  rel1 = (cx0 - ((float)(2 * ix + 1) * (1.0f / WF) - 1.0f)) * (float)WF;
}

// Blend weight for tap t, query q: preds[t] pairs with areas[3-t].
__device__ __forceinline__ float blend_wt(int q, int t) {
  float a[4], tot = 0.0f;
#pragma unroll
  for (int u = 0; u < 4; ++u) {
    int p; float r0, r1;
    tap_geom(q, (u & 2) ? 1.0f : -1.0f, (u & 1) ? 1.0f : -1.0f, p, r0, r1);
    a[u] = fabsf(r0 * r1) + 1e-9f;
    tot += a[u];
  }
  float sel = (t == 0) ? a[3] : (t == 1) ? a[2] : (t == 2) ? a[1] : a[0];
  return sel / tot;
}

// One hidden layer on the shared 128-row tile, in place. R3's exact k-loop
// schedule, except: s=0's mt=0,1 A-frags arrive prefetched (apre0/1, loaded
// before the PREVIOUS barrier), and before this layer's pre-epilogue
// barrier we issue the NEXT layer's s=0 frags into apre0/1.
template <int KSTEPS, int KPAD>
__device__ __forceinline__ void mlp_layer(f16* X, const f16* __restrict__ wt,
                                          const float* __restrict__ bv,
                                          int wv, int col, int quad,
                                          f16x8& apre0, f16x8& apre1,
                                          const f16* __restrict__ nxt,
                                          int nstride) {
  f32x4 acc[4][8];
#pragma unroll
  for (int mt = 0; mt < 4; ++mt)
#pragma unroll
    for (int nt = 0; nt < 8; ++nt) acc[mt][nt] = 0.0f;

  const f16* ap = wt + (wv * 64 + col) * KPAD + quad * 8;  // A[m=col+16mt][k]
  const f16* bp = X + col * STR + quad * 8;                // B[n=col+16nt][k]

  // ---- s = 0 (peeled): mt=0,1 from prefetch; mt=2,3 inline ----
  {
    f16x8 b[8];
#pragma unroll
    for (int nt = 0; nt < 8; ++nt)
      b[nt] = *(const f16x8*)(bp + nt * 16 * STR);
#pragma unroll
    for (int nt = 0; nt < 8; ++nt) acc[0][nt] = MFMA(apre0, b[nt], acc[0][nt]);
#pragma unroll
    for (int nt = 0; nt < 8; ++nt) acc[1][nt] = MFMA(apre1, b[nt], acc[1][nt]);
#pragma unroll
    for (int mt = 2; mt < 4; ++mt) {
      f16x8 a = *(const f16x8*)(ap + mt * 16 * KPAD);
#pragma unroll
      for (int nt = 0; nt < 8; ++nt) acc[mt][nt] = MFMA(a, b[nt], acc[mt][nt]);
    }
  }
  // ---- s = 1..KSTEPS-1: identical to the proven R3 schedule ----
#pragma unroll 1
  for (int s = 1; s < KSTEPS; ++s) {
    f16x8 b[8];
#pragma unroll
    for (int nt = 0; nt < 8; ++nt)
      b[nt] = *(const f16x8*)(bp + s * 32 + nt * 16 * STR);
#pragma unroll
    for (int mt = 0; mt < 4; ++mt) {
      f16x8 a = *(const f16x8*)(ap + s * 32 + mt * 16 * KPAD);
#pragma unroll
      for (int nt = 0; nt < 8; ++nt) acc[mt][nt] = MFMA(a, b[nt], acc[mt][nt]);
    }
  }

  // Prefetch the NEXT consumer's s=0 A-frags; these global loads stay in
  // flight across the lgkm-only barriers and the epilogue (~600+cy window).
  apre0 = *(const f16x8*)(nxt);
  apre1 = *(const f16x8*)(nxt + nstride);

  bar();   // all reads of X done before overwrite (lgkm-only)
  // D: row(m=feat) = mt*16 + quad*4 + i, col(n=query) = nt*16 + col.
#pragma unroll
  for (int mt = 0; mt < 4; ++mt) {
    float4 bb = *(const float4*)(bv + wv * 64 + mt * 16 + quad * 4);
#pragma unroll
    for (int nt = 0; nt < 8; ++nt) {
      f16x4 y;
      y[0] = (f16)fmaxf(acc[mt][nt][0] + bb.x, 0.0f);
      y[1] = (f16)fmaxf(acc[mt][nt][1] + bb.y, 0.0f);
      y[2] = (f16)fmaxf(acc[mt][nt][2] + bb.z, 0.0f);
      y[3] = (f16)fmaxf(acc[mt][nt][3] + bb.w, 0.0f);
      *(f16x4*)(X + (nt * 16 + col) * STR + wv * 64 + mt * 16 + quad * 4) = y;
    }
  }
  bar();
}

__global__ __launch_bounds__(256, 2) void liif_main(
    const f16* __restrict__ featT,
    const f16* __restrict__ wt0, const f16* __restrict__ wt1,
    const f16* __restrict__ wt2, const f16* __restrict__ wt3,
    const f16* __restrict__ wt4,
    const float* __restrict__ b0, const float* __restrict__ b1,
    const float* __restrict__ b2, const float* __restrict__ b3,
    const float* __restrict__ b4, float* __restrict__ out) {
  __shared__ __attribute__((aligned(16))) f16 X[R * STR];   // 67.6 KB
  const int tid = threadIdx.x;
  const int wv = tid >> 6;
  const int lane = tid & 63;
  const int row0 = blockIdx.x * R;               // rows = n*Q + q, 128 per block
  const int n = row0 >> 16;
  const int q0 = row0 & (Q - 1);
  const int col = lane & 15, quad = lane >> 4;

  float oacc[2][4] = {{0, 0, 0, 0}, {0, 0, 0, 0}};
  float bias4[4];
#pragma unroll
  for (int i = 0; i < 4; ++i) bias4[i] = (i < 3) ? b4[i] : 0.0f;

  // Per-layer A base pointers for this thread (prefetch chain targets).
  const f16* a0b = wt0 + (wv * 64 + col) * K0P + quad * 8;
  const f16* a1b = wt1 + (wv * 64 + col) * D + quad * 8;
  const f16* a2b = wt2 + (wv * 64 + col) * D + quad * 8;
  const f16* a3b = wt3 + (wv * 64 + col) * D + quad * 8;
  const f16* a4b = wt4 + col * D + quad * 8;     // final layer (frags = s=0,1)

  // Initial prefetch: layer 0, s=0, mt=0,1.
  f16x8 apre0 = *(const f16x8*)(a0b);
  f16x8 apre1 = *(const f16x8*)(a0b + 16 * K0P);

#pragma unroll 1
  for (int t = 0; t < 4; ++t) {
    const float vx = (t & 2) ? 1.0f : -1.0f;
    const float vy = (t & 1) ? 1.0f : -1.0f;

    bar();   // previous tap's reads of X complete
    // ---- gather X0: 64 feat + rel(2) + rel_cell(2), pad to 96 ----
    {
      const int gr = tid >> 1, hf = tid & 1;   // 2 threads per row, 64 B each
      int p; float r0, r1;
      tap_geom(q0 + gr, vx, vy, p, r0, r1);
      const f16x8* src = (const f16x8*)(featT + (((size_t)n << 12) + p) * 64 + hf * 32);
      f16x8* dst = (f16x8*)(X + gr * STR + hf * 32);
      dst[0] = src[0]; dst[1] = src[1]; dst[2] = src[2]; dst[3] = src[3];
      if (tid < R) {
        int p2; float s0, s1;
        tap_geom(q0 + tid, vx, vy, p2, s0, s1);
        f16* xr = X + tid * STR;
        f16x4 relv = {(f16)s0, (f16)s1, (f16)0.5f, (f16)0.5f};
        *(f16x4*)(xr + 64) = relv;
        f16x4 z4 = {0, 0, 0, 0};
        f16x8 z8 = {0, 0, 0, 0, 0, 0, 0, 0};
        *(f16x4*)(xr + 68) = z4;     // zero pad cols 68..95
        *(f16x8*)(xr + 72) = z8;
        *(f16x8*)(xr + 80) = z8;
        *(f16x8*)(xr + 88) = z8;
      }
    }
    bar();

    mlp_layer<3, K0P>(X, wt0, b0, wv, col, quad, apre0, apre1, a1b, 16 * D);
    mlp_layer<8, D>(X, wt1, b1, wv, col, quad, apre0, apre1, a2b, 16 * D);
    mlp_layer<8, D>(X, wt2, b2, wv, col, quad, apre0, apre1, a3b, 16 * D);
    mlp_layer<8, D>(X, wt3, b3, wv, col, quad, apre0, apre1, a4b, 32);

    // ---- final layer 256 -> 16 (3 real feats); wave handles its 32 queries ----
    // s=0,1 A-frags arrive prefetched (apre0/1); s>=2 inline as before.
    f32x4 facc[2];
    facc[0] = 0.0f; facc[1] = 0.0f;
    {
      const f16* bp = X + (wv * 32 + col) * STR + quad * 8;  // B[n=query]
      f16x8 bq0 = *(const f16x8*)(bp);
      f16x8 bq1 = *(const f16x8*)(bp + 16 * STR);
      facc[0] = MFMA(apre0, bq0, facc[0]);
      facc[1] = MFMA(apre0, bq1, facc[1]);
      bq0 = *(const f16x8*)(bp + 32);
      bq1 = *(const f16x8*)(bp + 16 * STR + 32);
      facc[0] = MFMA(apre1, bq0, facc[0]);
      facc[1] = MFMA(apre1, bq1, facc[1]);
#pragma unroll 1
      for (int s = 2; s < 8; ++s) {
        f16x8 a = *(const f16x8*)(a4b + s * 32);
        f16x8 c0 = *(const f16x8*)(bp + s * 32);
        f16x8 c1 = *(const f16x8*)(bp + 16 * STR + s * 32);
        facc[0] = MFMA(a, c0, facc[0]);
        facc[1] = MFMA(a, c1, facc[1]);
      }
    }
    // D: row=feat=quad*4+i, col=query. Blend into oacc.
#pragma unroll
    for (int nt = 0; nt < 2; ++nt) {
      int q = q0 + wv * 32 + nt * 16 + col;
      float w = blend_wt(q, t);
#pragma unroll
      for (int i = 0; i < 4; ++i) oacc[nt][i] += (facc[nt][i] + bias4[i]) * w;
    }

    // Prefetch layer-0 A for the NEXT tap (crosses tap barrier + gather).
    apre0 = *(const f16x8*)(a0b);
    apre1 = *(const f16x8*)(a0b + 16 * K0P);
  }

  // out[n][c][q]; lanes with quad==0 hold feats 0..3 (3 real) for their queries
  if (quad == 0) {
#pragma unroll
    for (int nt = 0; nt < 2; ++nt) {
      int q = q0 + wv * 32 + nt * 16 + col;
#pragma unroll
      for (int c = 0; c < 3; ++c)
        out[(((size_t)(n * 3 + c)) << 16) + q] = oacc[nt][c];
    }
  }
}

extern "C" void kernel_launch(void* const* d_in, const int* in_sizes, int n_in,
                              void* d_out, int out_size, void* d_ws, size_t ws_size,
                              hipStream_t stream) {
  const float* feat = (const float*)d_in[0];
  const float* w0 = (const float*)d_in[1];
  const float* b0 = (const float*)d_in[2];
  const float* w1 = (const float*)d_in[3];
  const float* b1 = (const float*)d_in[4];
  const float* w2 = (const float*)d_in[5];
  const float* b2 = (const float*)d_in[6];
  const float* w3 = (const float*)d_in[7];
  const float* b3 = (const float*)d_in[8];
  const float* w4 = (const float*)d_in[9];
  const float* b4 = (const float*)d_in[10];

  char* ws = (char*)d_ws;
  f16* featT = (f16*)(ws + OFF_FEAT);
  f16* wt0 = (f16*)(ws + OFF_W0);
  f16* wt1 = (f16*)(ws + OFF_W1);
  f16* wt2 = (f16*)(ws + OFF_W2);
  f16* wt3 = (f16*)(ws + OFF_W3);
  f16* wt4 = (f16*)(ws + OFF_W4);

  prep_feat<<<4096, 256, 0, stream>>>(feat, featT);
  prep_w<<<(256 * 96 + 255) / 256, 256, 0, stream>>>(w0, wt0, 68, 256, 96, 256);
  prep_w<<<256, 256, 0, stream>>>(w1, wt1, 256, 256, 256, 256);
  prep_w<<<256, 256, 0, stream>>>(w2, wt2, 256, 256, 256, 256);
  prep_w<<<256, 256, 0, stream>>>(w3, wt3, 256, 256, 256, 256);
  prep_w<<<(16 * 256 + 255) / 256, 256, 0, stream>>>(w4, wt4, 256, 3, 256, 16);

  liif_main<<<Q * 4 / R, 256, 0, stream>>>(featT, wt0, wt1, wt2, wt3, wt4,
                                           b0, b1, b2, b3, b4, (float*)d_out);
}